// Round 3
// baseline (994.465 us; speedup 1.0000x reference)
//
#include <hip/hip_runtime.h>

// VQ-VAE Quantize for MI355X (gfx950).
// N=65536 points, D=256 dims, K=4096 codes.
// Strategy: f16 MFMA GEMM for approximate distances + exact top-2 margin;
// rows with margin < TAU are re-ranked exactly (fp32 chunk-8 + fp64 accum).
// Partials are per (row, nb, wc) -> width 64, race-free.
// Workspace: ~95 MB.

typedef unsigned short u16;
typedef _Float16 f16;
typedef _Float16 f16x4 __attribute__((ext_vector_type(4)));
typedef _Float16 f16x8 __attribute__((ext_vector_type(8)));
typedef float f32x4 __attribute__((ext_vector_type(4)));

#define DECAYF 0.99f
#define ONE_MINUS_DECAYF 0.01f
#define EPSF 1e-5f
#define TAU 0.125f

// ---------- helpers ----------
__device__ __forceinline__ void gload16(const void* g, void* l) {
  __builtin_amdgcn_global_load_lds(
      (const __attribute__((address_space(1))) unsigned int*)g,
      (__attribute__((address_space(3))) unsigned int*)l, 16, 0, 0);
}
// XOR swizzle inside a [128 rows][64 f16] tile: permute 16B slots by row&7.
// Applied when WRITING the tiled global arrays (pre-kernels) and when READING
// fragments from LDS (global_load_lds copies tile->LDS linearly). Both-sides rule.
__device__ __forceinline__ int swz(int row, int col) {
  return row * 64 + ((((col >> 3) ^ row) & 7) << 3) + (col & 7);
}

// ---------- pre-kernels ----------
// z [65536][256] f32 -> Zh tiled [512 mt][4 kc][128 r][64 d] f16, swizzled
__global__ __launch_bounds__(256) void prep_z(const float* __restrict__ z,
                                              u16* __restrict__ Zh) {
  int bid = blockIdx.x;              // 2048 = 512 mt * 4 kc
  int mt = bid >> 2, kc = bid & 3;
  int t = threadIdx.x;
  size_t tb = (size_t)(mt * 4 + kc) * 8192;
#pragma unroll
  for (int it = 0; it < 8; ++it) {
    int i = it * 256 + t;            // 0..2047 float4 chunks
    int rr = i >> 4;                 // 0..127 row
    int dl = (i & 15) << 2;          // 0..60 col (float4)
    float4 v = *(const float4*)(z + (size_t)(mt * 128 + rr) * 256 + kc * 64 + dl);
    f16x4 h;
    h[0] = (f16)v.x; h[1] = (f16)v.y; h[2] = (f16)v.z; h[3] = (f16)v.w;
    *(f16x4*)(Zh + tb + swz(rr, dl)) = h;   // dl%8 in {0,4}: inside one 16B slot
  }
}

// embed [256][4096] f32 -> Bh tiled [32 nb][4 kc][128 n][64 d] f16 (transposed), swizzled
__global__ __launch_bounds__(256) void prep_embed(const float* __restrict__ embed,
                                                  u16* __restrict__ Bh) {
  __shared__ f16 Lh[8192];           // [64 d][128 n]
  int bid = blockIdx.x;              // 128 = 32 nb * 4 kc
  int nb = bid >> 2, kc = bid & 3;
  int t = threadIdx.x;
#pragma unroll
  for (int it = 0; it < 32; ++it) {
    int i = it * 256 + t;
    int dl = i >> 7, nl = i & 127;   // coalesced read over n
    float v = embed[(size_t)(kc * 64 + dl) * 4096 + nb * 128 + nl];
    Lh[dl * 128 + nl] = (f16)v;
  }
  __syncthreads();
  size_t tb = (size_t)(nb * 4 + kc) * 8192;
#pragma unroll
  for (int it = 0; it < 32; ++it) {
    int j = it * 256 + t;
    int nl = j >> 6, dl = j & 63;    // write transposed [n][d]
    *(f16*)(Bh + tb + swz(nl, dl)) = Lh[dl * 128 + nl];
  }
}

// e2[n] (f32) and e2d[n] (f64) = sum_d embed[d][n]^2 ; ET[n][d] = embed[d][n].
// Parallelized: 65536 threads, each owns (n, 16-d chunk); atomic combine.
__global__ __launch_bounds__(256) void prep_e2_et(const float* __restrict__ embed,
                                                  float* __restrict__ ET,
                                                  float* __restrict__ e2,
                                                  double* __restrict__ e2d) {
  int i = blockIdx.x * 256 + threadIdx.x;  // 65536 = 4096 n * 16 dq
  int n = i & 4095;
  int dq = i >> 12;                        // 0..15
  float c0 = 0.f, c1 = 0.f;
#pragma unroll
  for (int dd = 0; dd < 8; ++dd) {
    float v = embed[(size_t)(dq * 16 + dd) * 4096 + n];   // coalesced over n
    c0 += v * v;
    ET[(size_t)n * 256 + dq * 16 + dd] = v;
  }
#pragma unroll
  for (int dd = 8; dd < 16; ++dd) {
    float v = embed[(size_t)(dq * 16 + dd) * 4096 + n];
    c1 += v * v;
    ET[(size_t)n * 256 + dq * 16 + dd] = v;
  }
  atomicAdd(&e2d[n], (double)c0 + (double)c1);
  atomicAdd(&e2[n], c0 + c1);
}

// ---------- main GEMM + fused top-2 partial argmin ----------
// Grid: 16384 = 512 mt * 32 nb. Block 256 (4 waves, 2x2 over the 128x128 tile).
// K=256 (4 k-steps). Partials per (row, nb, wc): top-2 values + best idx.
__global__ __launch_bounds__(256, 3) void gemm_argmin(
    const u16* __restrict__ Zh, const u16* __restrict__ Bh,
    const float* __restrict__ e2,
    float* __restrict__ pv1, float* __restrict__ pv2, int* __restrict__ pi1) {
  __shared__ u16 As[8192];  // [128 m][64 d] swizzled
  __shared__ u16 Bs[8192];  // [128 n][64 d] swizzled
  int bid = blockIdx.x;
  int mt = bid >> 5;
  int nb = bid & 31;
  int tid = threadIdx.x;
  int lane = tid & 63;
  int w = tid >> 6;
  int wr = w >> 1, wc = w & 1;       // wave tile 64x64
  int g = lane >> 4, r = lane & 15;

  f32x4 acc[4][4] = {};
  int off = tid * 8;                 // f16 elems; 256 thr * 16B = 4KB per pass

  for (int kk = 0; kk < 4; ++kk) {
    const u16* at = Zh + (size_t)(mt * 4 + kk) * 8192;
    const u16* bt = Bh + (size_t)(nb * 4 + kk) * 8192;
    __syncthreads();                 // previous compute done reading LDS
#pragma unroll
    for (int i2 = 0; i2 < 4; ++i2) {
      gload16(at + i2 * 2048 + off, &As[i2 * 2048 + off]);
      gload16(bt + i2 * 2048 + off, &Bs[i2 * 2048 + off]);
    }
    __syncthreads();                 // drains vmcnt: staged data visible
#pragma unroll
    for (int kf = 0; kf < 2; ++kf) {
      f16x8 a[4], b[4];
#pragma unroll
      for (int rt = 0; rt < 4; ++rt)
        a[rt] = *(const f16x8*)(&As[swz(wr * 64 + rt * 16 + r, kf * 32 + g * 8)]);
#pragma unroll
      for (int ct = 0; ct < 4; ++ct)
        b[ct] = *(const f16x8*)(&Bs[swz(wc * 64 + ct * 16 + r, kf * 32 + g * 8)]);
#pragma unroll
      for (int rt = 0; rt < 4; ++rt)
#pragma unroll
        for (int ct = 0; ct < 4; ++ct)
          acc[rt][ct] = __builtin_amdgcn_mfma_f32_16x16x32_f16(
              a[rt], b[ct], acc[rt][ct], 0, 0, 0);
    }
  }

  // Epilogue: rel-dist = ||e||^2 - 2*S (||z||^2 is row-constant).
  // Exact top-2 tournament within this wave's 64 columns.
  float e2v[4];
#pragma unroll
  for (int ct = 0; ct < 4; ++ct) e2v[ct] = e2[nb * 128 + wc * 64 + ct * 16 + r];

#pragma unroll
  for (int rt = 0; rt < 4; ++rt) {
#pragma unroll
    for (int i = 0; i < 4; ++i) {    // C frag: row = g*4+i, col = r (m89/m91)
      float v1 = e2v[0] - 2.0f * acc[rt][0][i];
      int i1 = nb * 128 + wc * 64 + r;
      float v2 = 3.4e38f;
#pragma unroll
      for (int ct = 1; ct < 4; ++ct) {
        float v = e2v[ct] - 2.0f * acc[rt][ct][i];
        int ki = nb * 128 + wc * 64 + ct * 16 + r;
        if (v < v1 || (v == v1 && ki < i1)) { v2 = v1; v1 = v; i1 = ki; }
        else v2 = fminf(v2, v);
      }
#pragma unroll
      for (int mm = 1; mm < 16; mm <<= 1) {  // merge top-2 over the 16 r-lanes
        float ov1 = __shfl_xor(v1, mm);
        int   oi1 = __shfl_xor(i1, mm);
        float ov2 = __shfl_xor(v2, mm);
        if (ov1 < v1 || (ov1 == v1 && oi1 < i1)) { v2 = fminf(v1, ov2); v1 = ov1; i1 = oi1; }
        else v2 = fminf(v2, ov1);
      }
      if (r == 0) {
        int row = mt * 128 + wr * 64 + rt * 16 + g * 4 + i;
        size_t p = (size_t)row * 64 + nb * 2 + wc;   // RACE-FREE: wc in address
        pv1[p] = v1; pv2[p] = v2; pi1[p] = i1;
      }
    }
  }
}

// ---------- combine 64 partials/row -> idx + ambiguity flag ----------
__global__ __launch_bounds__(256) void combine(
    const float* __restrict__ pv1, const float* __restrict__ pv2,
    const int* __restrict__ pi1,
    int* __restrict__ idx32, int* __restrict__ fixlist, int* __restrict__ fixcount) {
  int wv = threadIdx.x >> 6, lane = threadIdx.x & 63;
  int row = blockIdx.x * 4 + wv;     // grid 16384
  size_t base = (size_t)row * 64 + lane;
  float v1 = pv1[base], v2 = pv2[base];
  int i1 = pi1[base];
#pragma unroll
  for (int mm = 1; mm < 64; mm <<= 1) {
    float ov1 = __shfl_xor(v1, mm);
    int   oi1 = __shfl_xor(i1, mm);
    float ov2 = __shfl_xor(v2, mm);
    if (ov1 < v1 || (ov1 == v1 && oi1 < i1)) { v2 = fminf(v1, ov2); v1 = ov1; i1 = oi1; }
    else v2 = fminf(v2, ov1);
  }
  if (lane == 0) {
    idx32[row] = i1;
    if (v2 - v1 < TAU) {             // ambiguous under f16 noise (~8 sigma)
      int p = atomicAdd(fixcount, 1);
      fixlist[p] = row;
    }
  }
}

// ---------- exact re-rank of flagged rows (fp32 chunk8 + fp64 accum) ----------
__global__ __launch_bounds__(256) void fixup(
    const float* __restrict__ z, const float* __restrict__ embed,
    const double* __restrict__ e2d, const int* __restrict__ fixlist,
    const int* __restrict__ fixcount, int* __restrict__ idx32) {
  __shared__ float zl[4][256];
  __shared__ double rv[4][4];
  __shared__ int ri[4][4];
  int count = *fixcount;
  for (int base = blockIdx.x * 4; base < count; base += 256 * 4) { // grid 256
    int nr = min(4, count - base);
    for (int i = threadIdx.x; i < 1024; i += 256) {
      int rr = i >> 8, d = i & 255;
      if (rr < nr) zl[rr][d] = z[(size_t)fixlist[base + rr] * 256 + d];
    }
    __syncthreads();
    double bestv[4] = {1e300, 1e300, 1e300, 1e300};
    int besti[4] = {0, 0, 0, 0};
    for (int c = 0; c < 16; ++c) {
      int k = c * 256 + threadIdx.x;
      double acc[4] = {0, 0, 0, 0};
      for (int d0 = 0; d0 < 256; d0 += 8) {
        float ch[4] = {0, 0, 0, 0};
#pragma unroll
        for (int dd = 0; dd < 8; ++dd) {
          float e = embed[(size_t)(d0 + dd) * 4096 + k];  // coalesced over k
#pragma unroll
          for (int rr = 0; rr < 4; ++rr) ch[rr] += zl[rr][d0 + dd] * e;
        }
#pragma unroll
        for (int rr = 0; rr < 4; ++rr) acc[rr] += (double)ch[rr];
      }
#pragma unroll
      for (int rr = 0; rr < 4; ++rr) {
        double dist = e2d[k] - 2.0 * acc[rr];
        if (dist < bestv[rr] || (dist == bestv[rr] && k < besti[rr])) {
          bestv[rr] = dist; besti[rr] = k;
        }
      }
    }
    int wv = threadIdx.x >> 6;
#pragma unroll
    for (int rr = 0; rr < 4; ++rr) {
      double v = bestv[rr]; int ii = besti[rr];
#pragma unroll
      for (int mm = 1; mm < 64; mm <<= 1) {
        double ov = __shfl_xor(v, mm);
        int oi = __shfl_xor(ii, mm);
        if (ov < v || (ov == v && oi < ii)) { v = ov; ii = oi; }
      }
      if ((threadIdx.x & 63) == 0) { rv[wv][rr] = v; ri[wv][rr] = ii; }
    }
    __syncthreads();
    if (threadIdx.x < nr) {
      int rr = threadIdx.x;
      double v = rv[0][rr]; int ii = ri[0][rr];
#pragma unroll
      for (int wvi = 1; wvi < 4; ++wvi) {
        double ov = rv[wvi][rr]; int oi = ri[wvi][rr];
        if (ov < v || (ov == v && oi < ii)) { v = ov; ii = oi; }
      }
      idx32[fixlist[base + rr]] = ii;
    }
    __syncthreads();                 // before next iteration reuses zl/rv/ri
  }
}

// ---------- per-row finalize: gather, quantize_st, diff, scatter stats ----------
__global__ __launch_bounds__(512) void finalize_rows(
    const float* __restrict__ z, const float* __restrict__ ET,
    const int* __restrict__ idx32,
    float* __restrict__ outq, float* __restrict__ outdiff,
    float* __restrict__ outind,
    float* __restrict__ EST, float* __restrict__ ntot) {
  __shared__ float dsum[8];
  int wv = threadIdx.x >> 6;
  int lane = threadIdx.x & 63;
  size_t row = (size_t)blockIdx.x * 8 + wv;   // one wave per z-row
  int idx = idx32[row];
  float4 zv = ((const float4*)(z + row * 256))[lane];
  float4 ev = ((const float4*)(ET + (size_t)idx * 256))[lane];
  // quantize_st = z + (q - z): replicate reference's op order exactly
  float4 qs;
  qs.x = zv.x + (ev.x - zv.x); qs.y = zv.y + (ev.y - zv.y);
  qs.z = zv.z + (ev.z - zv.z); qs.w = zv.w + (ev.w - zv.w);
  ((float4*)(outq + row * 256))[lane] = qs;
  float dx = ev.x - zv.x, dy = ev.y - zv.y, dz = ev.z - zv.z, dw = ev.w - zv.w;
  float s = dx * dx + dy * dy + dz * dz + dw * dw;
#pragma unroll
  for (int mm = 1; mm < 64; mm <<= 1) s += __shfl_xor(s, mm);
  if (lane == 0) {
    dsum[wv] = s;
    outind[row] = (float)idx;
    atomicAdd(&ntot[idx], 1.0f);
  }
  float* ep = EST + (size_t)idx * 256 + lane * 4;   // EST layout [K][D]
  atomicAdd(ep + 0, zv.x);
  atomicAdd(ep + 1, zv.y);
  atomicAdd(ep + 2, zv.z);
  atomicAdd(ep + 3, zv.w);
  __syncthreads();
  if (threadIdx.x == 0) {                     // one atomic per block
    float t = 0.f;
#pragma unroll
    for (int i = 0; i < 8; ++i) t += dsum[i];
    atomicAdd(outdiff, t * (1.0f / 16777216.0f));
  }
}

// ---------- codebook EMA finalize ----------
__global__ __launch_bounds__(256) void finalize_cs(const float* __restrict__ cs,
                                                   const float* __restrict__ ntot,
                                                   float* __restrict__ outncs,
                                                   float* __restrict__ nsum) {
  int k = blockIdx.x * 256 + threadIdx.x;     // 4096
  float v = cs[k] * DECAYF + ONE_MINUS_DECAYF * ntot[k];
  outncs[k] = v;
  float s = v;
#pragma unroll
  for (int mm = 1; mm < 64; mm <<= 1) s += __shfl_xor(s, mm);
  __shared__ float ws_[4];
  if ((threadIdx.x & 63) == 0) ws_[threadIdx.x >> 6] = s;
  __syncthreads();
  if (threadIdx.x == 0) atomicAdd(nsum, ws_[0] + ws_[1] + ws_[2] + ws_[3]);
}

__global__ __launch_bounds__(256) void finalize_embed(
    const float* __restrict__ eavg, const float* __restrict__ EST,
    const float* __restrict__ ncs, const float* __restrict__ nsum,
    float* __restrict__ outnea, float* __restrict__ outne) {
  int i = blockIdx.x * 256 + threadIdx.x;     // 1048576; layout [d][k]
  int d = i >> 12, k = i & 4095;
  float nea = eavg[i] * DECAYF + ONE_MINUS_DECAYF * EST[(size_t)k * 256 + d];
  float n = *nsum;
  float c = (ncs[k] + EPSF) / (n + 4096.0f * EPSF) * n;
  outnea[i] = nea;
  outne[i] = nea / c;
}

// ---------- launch ----------
extern "C" void kernel_launch(void* const* d_in, const int* in_sizes, int n_in,
                              void* d_out, int out_size, void* d_ws, size_t ws_size,
                              hipStream_t stream) {
  (void)in_sizes; (void)n_in; (void)out_size; (void)ws_size;
  const float* z     = (const float*)d_in[0];
  const float* embed = (const float*)d_in[1];
  const float* cs    = (const float*)d_in[2];
  const float* eavg  = (const float*)d_in[3];

  char* ws = (char*)d_ws;
  u16*    Zh    = (u16*)   (ws + 0);          // 33554432
  u16*    Bh    = (u16*)   (ws + 33554432);   //  2097152
  float*  ET    = (float*) (ws + 35651584);   //  4194304
  float*  e2    = (float*) (ws + 39845888);   //    16384
  double* e2d   = (double*)(ws + 39862272);   //    32768
  float*  EST   = (float*) (ws + 39895040);   //  4194304
  float*  ntot  = (float*) (ws + 44089344);   //    16384
  float*  nsum  = (float*) (ws + 44105728);   //      256
  int*    fixcount = (int*)(ws + 44105984);   //      256
  int*    fixlist  = (int*)(ws + 44106240);   //   262144
  int*    idx32 = (int*)   (ws + 44368384);   //   262144
  float*  pv1   = (float*) (ws + 44630528);   // 16777216
  float*  pv2   = (float*) (ws + 61407744);   // 16777216
  int*    pi1   = (int*)   (ws + 78184960);   // 16777216  -> end ~95 MB

  float* out     = (float*)d_out;
  float* outq    = out;                    // 16777216
  float* outdiff = out + 16777216;         // 1
  float* outind  = out + 16777217;         // 65536
  float* outne   = out + 16842753;         // 1048576 new_embed
  float* outncs  = out + 17891329;         // 4096    new_cluster_size
  float* outnea  = out + 17895425;         // 1048576 new_embed_avg

  hipMemsetAsync(e2, 0, 16384, stream);
  hipMemsetAsync(e2d, 0, 32768, stream);
  hipMemsetAsync(EST, 0, 4194304, stream);
  hipMemsetAsync(ntot, 0, 16384, stream);
  hipMemsetAsync(nsum, 0, 4, stream);
  hipMemsetAsync(fixcount, 0, 4, stream);
  hipMemsetAsync(outdiff, 0, 4, stream);

  prep_z<<<2048, 256, 0, stream>>>(z, Zh);
  prep_embed<<<128, 256, 0, stream>>>(embed, Bh);
  prep_e2_et<<<256, 256, 0, stream>>>(embed, ET, e2, e2d);
  gemm_argmin<<<16384, 256, 0, stream>>>(Zh, Bh, e2, pv1, pv2, pi1);
  combine<<<16384, 256, 0, stream>>>(pv1, pv2, pi1, idx32, fixlist, fixcount);
  fixup<<<256, 256, 0, stream>>>(z, embed, e2d, fixlist, fixcount, idx32);
  finalize_rows<<<8192, 512, 0, stream>>>(z, ET, idx32, outq, outdiff, outind, EST, ntot);
  finalize_cs<<<16, 256, 0, stream>>>(cs, ntot, outncs, nsum);
  finalize_embed<<<4096, 256, 0, stream>>>(eavg, EST, outncs, nsum, outnea, outne);
}